// Round 1
// baseline (2113.358 us; speedup 1.0000x reference)
//
#include <hip/hip_runtime.h>
#include <hip/hip_bf16.h>

typedef unsigned short u16;
typedef __attribute__((ext_vector_type(8))) __bf16 bf16x8;
typedef __attribute__((ext_vector_type(4))) float f32x4;

#define BB 2
#define LL 1024
#define DD 768
#define HH 12

// round-to-nearest-even f32 -> bf16
__device__ __forceinline__ u16 f2b(float v) {
  unsigned u = __builtin_bit_cast(unsigned, v);
  return (u16)((u + 0x7fffu + ((u >> 16) & 1u)) >> 16);
}

__global__ void k_cast(const float* __restrict__ in, u16* __restrict__ out, int n) {
  int i = blockIdx.x * blockDim.x + threadIdx.x;
  if (i < n) out[i] = f2b(in[i]);
}

// ---------------------------------------------------------------------------
// C[m,n] = sum_k A[m,k] * Bt[n,k]  (both bf16, fp32 accum). 64x64 tile, BK=32.
// Batched: z -> (zb, zh) with strides in ELEMENT units of each array.
// ---------------------------------------------------------------------------
__global__ __launch_bounds__(256) void k_gemm_nt(
    const u16* __restrict__ A, int lda, long long sAb, long long sAh,
    const u16* __restrict__ Bt, int ldb, long long sBb, long long sBh,
    float* __restrict__ Cf, u16* __restrict__ Cb, int ldc, long long sCb, long long sCh,
    const float* __restrict__ bias, int M, int N, int K, int nInner)
{
  __shared__ __align__(16) u16 As[64][40];
  __shared__ __align__(16) u16 Bs[64][40];
  int z = blockIdx.z, zb = z / nInner, zh = z - zb * nInner;
  A  += zb * sAb + zh * sAh;
  Bt += zb * sBb + zh * sBh;
  long long coff = zb * sCb + zh * sCh;
  int m0 = blockIdx.y * 64, n0 = blockIdx.x * 64;
  int tid = threadIdx.x, lane = tid & 63, w = tid >> 6;
  int wm = (w >> 1) * 32, wn = (w & 1) * 32;
  int arow = tid >> 2, acol = (tid & 3) * 8;
  int frow = lane & 15, kf = (lane >> 4) * 8;
  f32x4 acc[2][2] = {};
  for (int k0 = 0; k0 < K; k0 += 32) {
    *(uint4*)&As[arow][acol] = *(const uint4*)&A[(size_t)(m0 + arow) * lda + k0 + acol];
    *(uint4*)&Bs[arow][acol] = *(const uint4*)&Bt[(size_t)(n0 + arow) * ldb + k0 + acol];
    __syncthreads();
    bf16x8 af0 = *(const bf16x8*)&As[wm + frow][kf];
    bf16x8 af1 = *(const bf16x8*)&As[wm + 16 + frow][kf];
    bf16x8 bg0 = *(const bf16x8*)&Bs[wn + frow][kf];
    bf16x8 bg1 = *(const bf16x8*)&Bs[wn + 16 + frow][kf];
    acc[0][0] = __builtin_amdgcn_mfma_f32_16x16x32_bf16(af0, bg0, acc[0][0], 0, 0, 0);
    acc[0][1] = __builtin_amdgcn_mfma_f32_16x16x32_bf16(af0, bg1, acc[0][1], 0, 0, 0);
    acc[1][0] = __builtin_amdgcn_mfma_f32_16x16x32_bf16(af1, bg0, acc[1][0], 0, 0, 0);
    acc[1][1] = __builtin_amdgcn_mfma_f32_16x16x32_bf16(af1, bg1, acc[1][1], 0, 0, 0);
    __syncthreads();
  }
  int cr = (lane >> 4) * 4, cc = lane & 15;
  for (int mi = 0; mi < 2; mi++)
    for (int ni = 0; ni < 2; ni++) {
      int col = n0 + wn + ni * 16 + cc;
      float bval = bias ? bias[col] : 0.f;
      #pragma unroll
      for (int j = 0; j < 4; j++) {
        int row = m0 + wm + mi * 16 + cr + j;
        float v = acc[mi][ni][j] + bval;
        size_t idx = (size_t)coff + (size_t)row * ldc + col;
        if (Cf) Cf[idx] = v;
        if (Cb) Cb[idx] = f2b(v);
      }
    }
}

// ---------------------------------------------------------------------------
// C[m,n] = sum_k A[m,k] * B[k,n]  (row-major B). Same tiling; B staged transposed.
// ---------------------------------------------------------------------------
__global__ __launch_bounds__(256) void k_gemm_nn(
    const u16* __restrict__ A, int lda, long long sAb, long long sAh,
    const u16* __restrict__ Bm, int ldb, long long sBb, long long sBh,
    float* __restrict__ Cf, u16* __restrict__ Cb, int ldc, long long sCb, long long sCh,
    const float* __restrict__ bias, int M, int N, int K, int nInner)
{
  __shared__ __align__(16) u16 As[64][40];
  __shared__ __align__(16) u16 Bs[64][40];
  int z = blockIdx.z, zb = z / nInner, zh = z - zb * nInner;
  A  += zb * sAb + zh * sAh;
  Bm += zb * sBb + zh * sBh;
  long long coff = zb * sCb + zh * sCh;
  int m0 = blockIdx.y * 64, n0 = blockIdx.x * 64;
  int tid = threadIdx.x, lane = tid & 63, w = tid >> 6;
  int wm = (w >> 1) * 32, wn = (w & 1) * 32;
  int arow = tid >> 2, acol = (tid & 3) * 8;
  int brow = tid >> 3, bcol = (tid & 7) * 8;  // brow = k (0..31), bcol = n
  int frow = lane & 15, kf = (lane >> 4) * 8;
  f32x4 acc[2][2] = {};
  for (int k0 = 0; k0 < K; k0 += 32) {
    *(uint4*)&As[arow][acol] = *(const uint4*)&A[(size_t)(m0 + arow) * lda + k0 + acol];
    union { uint4 v; u16 s[8]; } t4;
    t4.v = *(const uint4*)&Bm[(size_t)(k0 + brow) * ldb + n0 + bcol];
    #pragma unroll
    for (int j = 0; j < 8; j++) Bs[bcol + j][brow] = t4.s[j];
    __syncthreads();
    bf16x8 af0 = *(const bf16x8*)&As[wm + frow][kf];
    bf16x8 af1 = *(const bf16x8*)&As[wm + 16 + frow][kf];
    bf16x8 bg0 = *(const bf16x8*)&Bs[wn + frow][kf];
    bf16x8 bg1 = *(const bf16x8*)&Bs[wn + 16 + frow][kf];
    acc[0][0] = __builtin_amdgcn_mfma_f32_16x16x32_bf16(af0, bg0, acc[0][0], 0, 0, 0);
    acc[0][1] = __builtin_amdgcn_mfma_f32_16x16x32_bf16(af0, bg1, acc[0][1], 0, 0, 0);
    acc[1][0] = __builtin_amdgcn_mfma_f32_16x16x32_bf16(af1, bg0, acc[1][0], 0, 0, 0);
    acc[1][1] = __builtin_amdgcn_mfma_f32_16x16x32_bf16(af1, bg1, acc[1][1], 0, 0, 0);
    __syncthreads();
  }
  int cr = (lane >> 4) * 4, cc = lane & 15;
  for (int mi = 0; mi < 2; mi++)
    for (int ni = 0; ni < 2; ni++) {
      int col = n0 + wn + ni * 16 + cc;
      float bval = bias ? bias[col] : 0.f;
      #pragma unroll
      for (int j = 0; j < 4; j++) {
        int row = m0 + wm + mi * 16 + cr + j;
        float v = acc[mi][ni][j] + bval;
        size_t idx = (size_t)coff + (size_t)row * ldc + col;
        if (Cf) Cf[idx] = v;
        if (Cb) Cb[idx] = f2b(v);
      }
    }
}

// ---------------------------------------------------------------------------
// scores[b,h,l,r] += rel[b,l,r,:] . (rq[b,l,h*64+:] + rk[b,r,h*64+:])
// WG = (b, 8 consecutive l). 8 l-groups x 32 lanes; each lane: 2 r's per step.
// ---------------------------------------------------------------------------
__global__ __launch_bounds__(256) void k_relterms(
    const float* __restrict__ rel, const float* __restrict__ rqf,
    const float* __restrict__ rkf, float* __restrict__ scores)
{
  __shared__ __align__(16) float rqs[8][776];  // +8 pad -> group reads 2-way (free)
  int blk = blockIdx.x;
  int b = blk >> 7;
  int l0 = (blk & 127) << 3;
  int tid = threadIdx.x;
  for (int j = 0; j < 24; j++) {
    int i = j * 256 + tid;
    int rr = i / 768, cc2 = i - rr * 768;
    rqs[rr][cc2] = rqf[((size_t)b * LL + l0 + rr) * DD + cc2];
  }
  __syncthreads();
  int g = tid >> 5, tr = tid & 31;
  int l = l0 + g;
  const float4* rq4 = (const float4*)&rqs[g][0];
  for (int rt = 0; rt < 16; rt++) {
    int r0 = rt * 64 + tr;
    const float4* rel0 = (const float4*)(rel + (((size_t)b * LL + l) * LL + r0) * 64);
    const float4* rel1 = rel0 + 512;   // r0 + 32
    const float4* rk0 = (const float4*)(rkf + ((size_t)b * LL + r0) * DD);
    const float4* rk1 = rk0 + 6144;    // r0 + 32
    float s0[12], s1[12];
    #pragma unroll
    for (int h = 0; h < 12; h++) { s0[h] = 0.f; s1[h] = 0.f; }
    for (int db = 0; db < 16; db++) {
      float4 v0 = rel0[db], v1 = rel1[db];
      #pragma unroll
      for (int h = 0; h < 12; h++) {
        float4 a = rq4[h * 16 + db];
        float4 p = rk0[h * 16 + db];
        float4 q = rk1[h * 16 + db];
        s0[h] += v0.x * (a.x + p.x) + v0.y * (a.y + p.y) + v0.z * (a.z + p.z) + v0.w * (a.w + p.w);
        s1[h] += v1.x * (a.x + q.x) + v1.y * (a.y + q.y) + v1.z * (a.z + q.z) + v1.w * (a.w + q.w);
      }
    }
    #pragma unroll
    for (int h = 0; h < 12; h++) {
      size_t idx = ((size_t)(b * HH + h) * LL + l) * LL + r0;
      scores[idx] += s0[h];
      scores[idx + 32] += s1[h];
    }
  }
}

// ---------------------------------------------------------------------------
// Row softmax: x = scores/sqrt(192) + mask[b,r]; probs written bf16 IN-PLACE
// into the row's region (ushort lda = 2048 per row). Reads precede writes
// (separated by barriers) so in-place is race-free.
// ---------------------------------------------------------------------------
__global__ __launch_bounds__(256) void k_softmax(float* __restrict__ scores,
                                                 const float* __restrict__ mask)
{
  __shared__ float red[4];
  int z = blockIdx.x;            // (b*H + h)*L + l
  int b = z / (HH * LL);
  float* row = scores + (size_t)z * LL;
  int tid = threadIdx.x;
  const float inv = 0.07216878364870322f;  // 1/sqrt(192)
  float4 x = ((const float4*)row)[tid];
  float4 mk = ((const float4*)(mask + (size_t)b * LL))[tid];
  x.x = x.x * inv + mk.x; x.y = x.y * inv + mk.y;
  x.z = x.z * inv + mk.z; x.w = x.w * inv + mk.w;
  float m = fmaxf(fmaxf(x.x, x.y), fmaxf(x.z, x.w));
  for (int i = 1; i < 64; i <<= 1) m = fmaxf(m, __shfl_xor(m, i));
  if ((tid & 63) == 0) red[tid >> 6] = m;
  __syncthreads();
  m = fmaxf(fmaxf(red[0], red[1]), fmaxf(red[2], red[3]));
  float e0 = expf(x.x - m), e1 = expf(x.y - m), e2 = expf(x.z - m), e3 = expf(x.w - m);
  float s = e0 + e1 + e2 + e3;
  for (int i = 1; i < 64; i <<= 1) s += __shfl_xor(s, i);
  __syncthreads();
  if ((tid & 63) == 0) red[tid >> 6] = s;
  __syncthreads();
  float rs = 1.f / (red[0] + red[1] + red[2] + red[3]);
  u16* prow = (u16*)row;
  ushort4 o;
  o.x = f2b(e0 * rs); o.y = f2b(e1 * rs); o.z = f2b(e2 * rs); o.w = f2b(e3 * rs);
  ((ushort4*)prow)[tid] = o;
}

extern "C" void kernel_launch(void* const* d_in, const int* in_sizes, int n_in,
                              void* d_out, int out_size, void* d_ws, size_t ws_size,
                              hipStream_t stream)
{
  const float* hs   = (const float*)d_in[0];
  const float* mask = (const float*)d_in[1];
  const float* rel  = (const float*)d_in[2];
  const float* Wq   = (const float*)d_in[3];
  const float* Wk   = (const float*)d_in[4];
  const float* Wv   = (const float*)d_in[5];
  const float* bv   = (const float*)d_in[6];
  const float* Wo   = (const float*)d_in[7];
  const float* bo   = (const float*)d_in[8];
  float* out = (float*)d_out;

  // workspace layout (~134 MB)
  size_t o = 0;
  char* wsb = (char*)d_ws;
  auto alc = [&](size_t bytes) { void* p = wsb + o; o += (bytes + 255) & ~(size_t)255; return p; };
  u16* hs_bf = (u16*)alc(2048ull * 768 * 2);
  u16* wq_bf = (u16*)alc(768ull * 768 * 2);
  u16* wk_bf = (u16*)alc(768ull * 768 * 2);
  u16* wv_bf = (u16*)alc(768ull * 768 * 2);
  u16* wo_bf = (u16*)alc(768ull * 768 * 2);
  u16* q_bf  = (u16*)alc(2048ull * 768 * 2);
  u16* k_bf  = (u16*)alc(2048ull * 768 * 2);
  u16* v_bf  = (u16*)alc(2048ull * 768 * 2);
  float* rq_f = (float*)alc(2048ull * 768 * 4);
  float* rk_f = (float*)alc(2048ull * 768 * 4);
  u16* att_bf = (u16*)alc(2048ull * 768 * 2);
  float* scores = (float*)alc((size_t)BB * HH * LL * LL * 4);
  (void)ws_size; (void)in_sizes; (void)n_in; (void)out_size;

  // 1) casts to bf16
  k_cast<<<dim3((1572864 + 255) / 256), dim3(256), 0, stream>>>(hs, hs_bf, 1572864);
  k_cast<<<dim3((589824 + 255) / 256), dim3(256), 0, stream>>>(Wq, wq_bf, 589824);
  k_cast<<<dim3((589824 + 255) / 256), dim3(256), 0, stream>>>(Wk, wk_bf, 589824);
  k_cast<<<dim3((589824 + 255) / 256), dim3(256), 0, stream>>>(Wv, wv_bf, 589824);
  k_cast<<<dim3((589824 + 255) / 256), dim3(256), 0, stream>>>(Wo, wo_bf, 589824);

  dim3 gP(768 / 64, 2048 / 64, 1);  // projection GEMMs
  // 2) q,k,v = hs @ W.T (+bv for v); bf16 outputs
  k_gemm_nt<<<gP, 256, 0, stream>>>(hs_bf, 768, 0, 0, wq_bf, 768, 0, 0,
                                    nullptr, q_bf, 768, 0, 0, nullptr, 2048, 768, 768, 1);
  k_gemm_nt<<<gP, 256, 0, stream>>>(hs_bf, 768, 0, 0, wk_bf, 768, 0, 0,
                                    nullptr, k_bf, 768, 0, 0, nullptr, 2048, 768, 768, 1);
  k_gemm_nt<<<gP, 256, 0, stream>>>(hs_bf, 768, 0, 0, wv_bf, 768, 0, 0,
                                    nullptr, v_bf, 768, 0, 0, bv, 2048, 768, 768, 1);
  // 3) rq = q @ Wk, rk = k @ Wq (fp32 outputs for VALU rel-terms)
  k_gemm_nn<<<gP, 256, 0, stream>>>(q_bf, 768, 0, 0, wk_bf, 768, 0, 0,
                                    rq_f, nullptr, 768, 0, 0, nullptr, 2048, 768, 768, 1);
  k_gemm_nn<<<gP, 256, 0, stream>>>(k_bf, 768, 0, 0, wq_bf, 768, 0, 0,
                                    rk_f, nullptr, 768, 0, 0, nullptr, 2048, 768, 768, 1);

  // 4) scores = q . k  per (b,h): batched NT GEMM, fp32 out
  dim3 gS(16, 16, 24);
  k_gemm_nt<<<gS, 256, 0, stream>>>(q_bf, 768, 786432LL, 64LL, k_bf, 768, 786432LL, 64LL,
                                    scores, nullptr, 1024, 12582912LL, 1048576LL,
                                    nullptr, 1024, 1024, 64, 12);
  // 5) scores += rel . (rq + rk)
  k_relterms<<<dim3(256), dim3(256), 0, stream>>>(rel, rq_f, rk_f, scores);
  // 6) softmax rows -> bf16 probs in place
  k_softmax<<<dim3(BB * HH * LL), dim3(256), 0, stream>>>(scores, mask);
  // 7) attended = probs @ v  per (b,h): NN GEMM, probs lda=2048 ushorts
  dim3 gPV(1, 16, 24);
  k_gemm_nn<<<gPV, 256, 0, stream>>>((u16*)scores, 2048, 25165824LL, 2097152LL,
                                     v_bf, 768, 786432LL, 64LL,
                                     nullptr, att_bf, 768, 786432LL, 64LL,
                                     nullptr, 1024, 64, 1024, 12);
  // 8) out = attended @ Wo.T + bo (fp32 out)
  k_gemm_nt<<<gP, 256, 0, stream>>>(att_bf, 768, 0, 0, wo_bf, 768, 0, 0,
                                    out, nullptr, 768, 0, 0, bo, 2048, 768, 768, 1);
}

// Round 2
// 1817.256 us; speedup vs baseline: 1.1629x; 1.1629x over previous
//
#include <hip/hip_runtime.h>
#include <hip/hip_bf16.h>

typedef unsigned short u16;
typedef __attribute__((ext_vector_type(8))) __bf16 bf16x8;
typedef __attribute__((ext_vector_type(4))) float f32x4;

#define BB 2
#define LL 1024
#define DD 768
#define HH 12

// round-to-nearest-even f32 -> bf16
__device__ __forceinline__ u16 f2b(float v) {
  unsigned u = __builtin_bit_cast(unsigned, v);
  return (u16)((u + 0x7fffu + ((u >> 16) & 1u)) >> 16);
}

__global__ void k_cast(const float* __restrict__ in, u16* __restrict__ out, int n) {
  int i = blockIdx.x * blockDim.x + threadIdx.x;
  if (i < n) out[i] = f2b(in[i]);
}

// ---------------------------------------------------------------------------
// C[m,n] = sum_k A[m,k] * Bt[n,k]  (both bf16, fp32 accum). 64x64 tile, BK=32.
// Batched: z -> (zb, zh) with strides in ELEMENT units of each array.
// ---------------------------------------------------------------------------
__global__ __launch_bounds__(256) void k_gemm_nt(
    const u16* __restrict__ A, int lda, long long sAb, long long sAh,
    const u16* __restrict__ Bt, int ldb, long long sBb, long long sBh,
    float* __restrict__ Cf, u16* __restrict__ Cb, int ldc, long long sCb, long long sCh,
    const float* __restrict__ bias, int M, int N, int K, int nInner)
{
  __shared__ __align__(16) u16 As[64][40];
  __shared__ __align__(16) u16 Bs[64][40];
  int z = blockIdx.z, zb = z / nInner, zh = z - zb * nInner;
  A  += zb * sAb + zh * sAh;
  Bt += zb * sBb + zh * sBh;
  long long coff = zb * sCb + zh * sCh;
  int m0 = blockIdx.y * 64, n0 = blockIdx.x * 64;
  int tid = threadIdx.x, lane = tid & 63, w = tid >> 6;
  int wm = (w >> 1) * 32, wn = (w & 1) * 32;
  int arow = tid >> 2, acol = (tid & 3) * 8;
  int frow = lane & 15, kf = (lane >> 4) * 8;
  f32x4 acc[2][2] = {};
  for (int k0 = 0; k0 < K; k0 += 32) {
    *(uint4*)&As[arow][acol] = *(const uint4*)&A[(size_t)(m0 + arow) * lda + k0 + acol];
    *(uint4*)&Bs[arow][acol] = *(const uint4*)&Bt[(size_t)(n0 + arow) * ldb + k0 + acol];
    __syncthreads();
    bf16x8 af0 = *(const bf16x8*)&As[wm + frow][kf];
    bf16x8 af1 = *(const bf16x8*)&As[wm + 16 + frow][kf];
    bf16x8 bg0 = *(const bf16x8*)&Bs[wn + frow][kf];
    bf16x8 bg1 = *(const bf16x8*)&Bs[wn + 16 + frow][kf];
    acc[0][0] = __builtin_amdgcn_mfma_f32_16x16x32_bf16(af0, bg0, acc[0][0], 0, 0, 0);
    acc[0][1] = __builtin_amdgcn_mfma_f32_16x16x32_bf16(af0, bg1, acc[0][1], 0, 0, 0);
    acc[1][0] = __builtin_amdgcn_mfma_f32_16x16x32_bf16(af1, bg0, acc[1][0], 0, 0, 0);
    acc[1][1] = __builtin_amdgcn_mfma_f32_16x16x32_bf16(af1, bg1, acc[1][1], 0, 0, 0);
    __syncthreads();
  }
  int cr = (lane >> 4) * 4, cc = lane & 15;
  for (int mi = 0; mi < 2; mi++)
    for (int ni = 0; ni < 2; ni++) {
      int col = n0 + wn + ni * 16 + cc;
      float bval = bias ? bias[col] : 0.f;
      #pragma unroll
      for (int j = 0; j < 4; j++) {
        int row = m0 + wm + mi * 16 + cr + j;
        float v = acc[mi][ni][j] + bval;
        size_t idx = (size_t)coff + (size_t)row * ldc + col;
        if (Cf) Cf[idx] = v;
        if (Cb) Cb[idx] = f2b(v);
      }
    }
}

// ---------------------------------------------------------------------------
// C[m,n] = sum_k A[m,k] * B[k,n]  (row-major B). Same tiling; B staged transposed.
// ---------------------------------------------------------------------------
__global__ __launch_bounds__(256) void k_gemm_nn(
    const u16* __restrict__ A, int lda, long long sAb, long long sAh,
    const u16* __restrict__ Bm, int ldb, long long sBb, long long sBh,
    float* __restrict__ Cf, u16* __restrict__ Cb, int ldc, long long sCb, long long sCh,
    const float* __restrict__ bias, int M, int N, int K, int nInner)
{
  __shared__ __align__(16) u16 As[64][40];
  __shared__ __align__(16) u16 Bs[64][40];
  int z = blockIdx.z, zb = z / nInner, zh = z - zb * nInner;
  A  += zb * sAb + zh * sAh;
  Bm += zb * sBb + zh * sBh;
  long long coff = zb * sCb + zh * sCh;
  int m0 = blockIdx.y * 64, n0 = blockIdx.x * 64;
  int tid = threadIdx.x, lane = tid & 63, w = tid >> 6;
  int wm = (w >> 1) * 32, wn = (w & 1) * 32;
  int arow = tid >> 2, acol = (tid & 3) * 8;
  int brow = tid >> 3, bcol = (tid & 7) * 8;  // brow = k (0..31), bcol = n
  int frow = lane & 15, kf = (lane >> 4) * 8;
  f32x4 acc[2][2] = {};
  for (int k0 = 0; k0 < K; k0 += 32) {
    *(uint4*)&As[arow][acol] = *(const uint4*)&A[(size_t)(m0 + arow) * lda + k0 + acol];
    union { uint4 v; u16 s[8]; } t4;
    t4.v = *(const uint4*)&Bm[(size_t)(k0 + brow) * ldb + n0 + bcol];
    #pragma unroll
    for (int j = 0; j < 8; j++) Bs[bcol + j][brow] = t4.s[j];
    __syncthreads();
    bf16x8 af0 = *(const bf16x8*)&As[wm + frow][kf];
    bf16x8 af1 = *(const bf16x8*)&As[wm + 16 + frow][kf];
    bf16x8 bg0 = *(const bf16x8*)&Bs[wn + frow][kf];
    bf16x8 bg1 = *(const bf16x8*)&Bs[wn + 16 + frow][kf];
    acc[0][0] = __builtin_amdgcn_mfma_f32_16x16x32_bf16(af0, bg0, acc[0][0], 0, 0, 0);
    acc[0][1] = __builtin_amdgcn_mfma_f32_16x16x32_bf16(af0, bg1, acc[0][1], 0, 0, 0);
    acc[1][0] = __builtin_amdgcn_mfma_f32_16x16x32_bf16(af1, bg0, acc[1][0], 0, 0, 0);
    acc[1][1] = __builtin_amdgcn_mfma_f32_16x16x32_bf16(af1, bg1, acc[1][1], 0, 0, 0);
    __syncthreads();
  }
  int cr = (lane >> 4) * 4, cc = lane & 15;
  for (int mi = 0; mi < 2; mi++)
    for (int ni = 0; ni < 2; ni++) {
      int col = n0 + wn + ni * 16 + cc;
      float bval = bias ? bias[col] : 0.f;
      #pragma unroll
      for (int j = 0; j < 4; j++) {
        int row = m0 + wm + mi * 16 + cr + j;
        float v = acc[mi][ni][j] + bval;
        size_t idx = (size_t)coff + (size_t)row * ldc + col;
        if (Cf) Cf[idx] = v;
        if (Cb) Cb[idx] = f2b(v);
      }
    }
}

// ---------------------------------------------------------------------------
// scores[b,h,l,r] += rel[b,l,r,:] . (rq[b,l,h*64+:] + rk[b,r,h*64+:])
// Grid: blk = ((b*128 + ltile)*8 + rchunk); block = 8 l-groups x 32 lanes.
// Each lane handles r-chunk*128 + {tr, tr+32} for rt in {0,1}; 12 h accums.
// ---------------------------------------------------------------------------
__global__ __launch_bounds__(256) void k_relterms(
    const float* __restrict__ rel, const float* __restrict__ rqf,
    const float* __restrict__ rkf, float* __restrict__ scores)
{
  __shared__ __align__(16) float rqs[8][776];  // +8 pad; row stride 3104B (16B-aligned)
  int blk = blockIdx.x;
  int rc = blk & 7;
  int t  = blk >> 3;
  int b  = t >> 7;
  int l0 = (t & 127) << 3;
  int tid = threadIdx.x;
  // stage rq rows [l0..l0+7][0..767] as float4 (192 float4/row, 1536 total)
  #pragma unroll
  for (int j = 0; j < 6; j++) {
    int i = j * 256 + tid;
    int rr = i / 192, cc = (i - rr * 192) * 4;
    *(float4*)&rqs[rr][cc] = *(const float4*)&rqf[((size_t)b * LL + l0 + rr) * DD + cc];
  }
  __syncthreads();
  int g = tid >> 5, tr = tid & 31;
  int l = l0 + g;
  const float4* rq4 = (const float4*)&rqs[g][0];
  #pragma unroll
  for (int rt = 0; rt < 2; rt++) {
    int r0 = rc * 128 + rt * 64 + tr;
    const float4* rel0 = (const float4*)(rel + (((size_t)b * LL + l) * LL + r0) * 64);
    const float4* rel1 = rel0 + 512;   // r0 + 32
    const float4* rk0 = (const float4*)(rkf + ((size_t)b * LL + r0) * DD);
    const float4* rk1 = rk0 + 6144;    // r0 + 32
    float s0[12], s1[12];
    #pragma unroll
    for (int h = 0; h < 12; h++) { s0[h] = 0.f; s1[h] = 0.f; }
    for (int db = 0; db < 16; db++) {
      float4 v0 = rel0[db], v1 = rel1[db];
      #pragma unroll
      for (int h = 0; h < 12; h++) {
        float4 a = rq4[h * 16 + db];
        float4 p = rk0[h * 16 + db];
        float4 q = rk1[h * 16 + db];
        s0[h] += v0.x * (a.x + p.x) + v0.y * (a.y + p.y) + v0.z * (a.z + p.z) + v0.w * (a.w + p.w);
        s1[h] += v1.x * (a.x + q.x) + v1.y * (a.y + q.y) + v1.z * (a.z + q.z) + v1.w * (a.w + q.w);
      }
    }
    #pragma unroll
    for (int h = 0; h < 12; h++) {
      size_t idx = ((size_t)(b * HH + h) * LL + l) * LL + r0;
      scores[idx] += s0[h];
      scores[idx + 32] += s1[h];
    }
  }
}

// ---------------------------------------------------------------------------
// Row softmax: x = scores/sqrt(192) + mask[b,r]; probs written bf16 IN-PLACE
// into the row's region (ushort lda = 2048 per row).
// ---------------------------------------------------------------------------
__global__ __launch_bounds__(256) void k_softmax(float* __restrict__ scores,
                                                 const float* __restrict__ mask)
{
  __shared__ float red[4];
  int z = blockIdx.x;            // (b*H + h)*L + l
  int b = z / (HH * LL);
  float* row = scores + (size_t)z * LL;
  int tid = threadIdx.x;
  const float inv = 0.07216878364870322f;  // 1/sqrt(192)
  float4 x = ((const float4*)row)[tid];
  float4 mk = ((const float4*)(mask + (size_t)b * LL))[tid];
  x.x = x.x * inv + mk.x; x.y = x.y * inv + mk.y;
  x.z = x.z * inv + mk.z; x.w = x.w * inv + mk.w;
  float m = fmaxf(fmaxf(x.x, x.y), fmaxf(x.z, x.w));
  for (int i = 1; i < 64; i <<= 1) m = fmaxf(m, __shfl_xor(m, i));
  if ((tid & 63) == 0) red[tid >> 6] = m;
  __syncthreads();
  m = fmaxf(fmaxf(red[0], red[1]), fmaxf(red[2], red[3]));
  float e0 = expf(x.x - m), e1 = expf(x.y - m), e2 = expf(x.z - m), e3 = expf(x.w - m);
  float s = e0 + e1 + e2 + e3;
  for (int i = 1; i < 64; i <<= 1) s += __shfl_xor(s, i);
  __syncthreads();
  if ((tid & 63) == 0) red[tid >> 6] = s;
  __syncthreads();
  float rs = 1.f / (red[0] + red[1] + red[2] + red[3]);
  u16* prow = (u16*)row;
  ushort4 o;
  o.x = f2b(e0 * rs); o.y = f2b(e1 * rs); o.z = f2b(e2 * rs); o.w = f2b(e3 * rs);
  ((ushort4*)prow)[tid] = o;
}

extern "C" void kernel_launch(void* const* d_in, const int* in_sizes, int n_in,
                              void* d_out, int out_size, void* d_ws, size_t ws_size,
                              hipStream_t stream)
{
  const float* hs   = (const float*)d_in[0];
  const float* mask = (const float*)d_in[1];
  const float* rel  = (const float*)d_in[2];
  const float* Wq   = (const float*)d_in[3];
  const float* Wk   = (const float*)d_in[4];
  const float* Wv   = (const float*)d_in[5];
  const float* bv   = (const float*)d_in[6];
  const float* Wo   = (const float*)d_in[7];
  const float* bo   = (const float*)d_in[8];
  float* out = (float*)d_out;

  // workspace layout (~134 MB)
  size_t o = 0;
  char* wsb = (char*)d_ws;
  auto alc = [&](size_t bytes) { void* p = wsb + o; o += (bytes + 255) & ~(size_t)255; return p; };
  u16* hs_bf = (u16*)alc(2048ull * 768 * 2);
  u16* wq_bf = (u16*)alc(768ull * 768 * 2);
  u16* wk_bf = (u16*)alc(768ull * 768 * 2);
  u16* wv_bf = (u16*)alc(768ull * 768 * 2);
  u16* wo_bf = (u16*)alc(768ull * 768 * 2);
  u16* q_bf  = (u16*)alc(2048ull * 768 * 2);
  u16* k_bf  = (u16*)alc(2048ull * 768 * 2);
  u16* v_bf  = (u16*)alc(2048ull * 768 * 2);
  float* rq_f = (float*)alc(2048ull * 768 * 4);
  float* rk_f = (float*)alc(2048ull * 768 * 4);
  u16* att_bf = (u16*)alc(2048ull * 768 * 2);
  float* scores = (float*)alc((size_t)BB * HH * LL * LL * 4);
  (void)ws_size; (void)in_sizes; (void)n_in; (void)out_size;

  // 1) casts to bf16
  k_cast<<<dim3((1572864 + 255) / 256), dim3(256), 0, stream>>>(hs, hs_bf, 1572864);
  k_cast<<<dim3((589824 + 255) / 256), dim3(256), 0, stream>>>(Wq, wq_bf, 589824);
  k_cast<<<dim3((589824 + 255) / 256), dim3(256), 0, stream>>>(Wk, wk_bf, 589824);
  k_cast<<<dim3((589824 + 255) / 256), dim3(256), 0, stream>>>(Wv, wv_bf, 589824);
  k_cast<<<dim3((589824 + 255) / 256), dim3(256), 0, stream>>>(Wo, wo_bf, 589824);

  dim3 gP(768 / 64, 2048 / 64, 1);  // projection GEMMs
  // 2) q,k,v = hs @ W.T (+bv for v); bf16 outputs
  k_gemm_nt<<<gP, 256, 0, stream>>>(hs_bf, 768, 0, 0, wq_bf, 768, 0, 0,
                                    nullptr, q_bf, 768, 0, 0, nullptr, 2048, 768, 768, 1);
  k_gemm_nt<<<gP, 256, 0, stream>>>(hs_bf, 768, 0, 0, wk_bf, 768, 0, 0,
                                    nullptr, k_bf, 768, 0, 0, nullptr, 2048, 768, 768, 1);
  k_gemm_nt<<<gP, 256, 0, stream>>>(hs_bf, 768, 0, 0, wv_bf, 768, 0, 0,
                                    nullptr, v_bf, 768, 0, 0, bv, 2048, 768, 768, 1);
  // 3) rq = q @ Wk, rk = k @ Wq (fp32 outputs for VALU rel-terms)
  k_gemm_nn<<<gP, 256, 0, stream>>>(q_bf, 768, 0, 0, wk_bf, 768, 0, 0,
                                    rq_f, nullptr, 768, 0, 0, nullptr, 2048, 768, 768, 1);
  k_gemm_nn<<<gP, 256, 0, stream>>>(k_bf, 768, 0, 0, wq_bf, 768, 0, 0,
                                    rk_f, nullptr, 768, 0, 0, nullptr, 2048, 768, 768, 1);

  // 4) scores = q . k  per (b,h): batched NT GEMM, fp32 out
  dim3 gS(16, 16, 24);
  k_gemm_nt<<<gS, 256, 0, stream>>>(q_bf, 768, 786432LL, 64LL, k_bf, 768, 786432LL, 64LL,
                                    scores, nullptr, 1024, 12582912LL, 1048576LL,
                                    nullptr, 1024, 1024, 64, 12);
  // 5) scores += rel . (rq + rk)   — grid: 2 b x 128 l-tiles x 8 r-chunks
  k_relterms<<<dim3(2048), dim3(256), 0, stream>>>(rel, rq_f, rk_f, scores);
  // 6) softmax rows -> bf16 probs in place
  k_softmax<<<dim3(BB * HH * LL), dim3(256), 0, stream>>>(scores, mask);
  // 7) attended = probs @ v  per (b,h): NN GEMM, probs lda=2048 ushorts
  dim3 gPV(1, 16, 24);
  k_gemm_nn<<<gPV, 256, 0, stream>>>((u16*)scores, 2048, 25165824LL, 2097152LL,
                                     v_bf, 768, 786432LL, 64LL,
                                     nullptr, att_bf, 768, 786432LL, 64LL,
                                     nullptr, 1024, 64, 1024, 12);
  // 8) out = attended @ Wo.T + bo (fp32 out)
  k_gemm_nt<<<gP, 256, 0, stream>>>(att_bf, 768, 0, 0, wo_bf, 768, 0, 0,
                                    out, nullptr, 768, 0, 0, bo, 2048, 768, 768, 1);
}